// Round 3
// baseline (5891.509 us; speedup 1.0000x reference)
//
#include <hip/hip_runtime.h>
#include <hip/hip_bf16.h>
#include <math.h>

#define BATCH 4
#define SEQ   2048
#define DIM   1024
#define MROWS (SEQ*BATCH)          // 8192
#define BIGN  ((size_t)MROWS*DIM)  // 8388608 floats per buffer

typedef float v2f __attribute__((ext_vector_type(2)));

// ---------------- chunked scan for r_t = dec*r + k*v,  ret = q*r --------------
__global__ __launch_bounds__(256) void scan_a(const float* __restrict__ K,
    const float* __restrict__ V, const float* __restrict__ dec_p,
    float* __restrict__ E)
{
  int id  = blockIdx.x*256 + threadIdx.x;   // 0..262143
  int c   = id >> 12;
  int rem = id & 4095;
  int b   = rem >> 10;
  int dc  = rem & 1023;
  float dec = dec_p[dc >> 6];
  size_t base = ((size_t)b*SEQ + (size_t)c*32)*DIM + dc;
  float r = 0.f;
  #pragma unroll 4
  for (int i = 0; i < 32; ++i) {
    float kv = K[base + (size_t)i*DIM] * V[base + (size_t)i*DIM];
    r = fmaf(dec, r, kv);
  }
  E[(size_t)c*4096 + rem] = r;
}

__global__ __launch_bounds__(256) void scan_b(const float* __restrict__ E,
    const float* __restrict__ dec_p, float* __restrict__ carry)
{
  int id = blockIdx.x*256 + threadIdx.x;    // 0..4095
  int dc = id & 1023;
  float dec = dec_p[dc >> 6];
  float d2 = dec*dec, d4 = d2*d2, d8 = d4*d4, d16 = d8*d8, d32 = d16*d16;
  float r = 0.f;
  #pragma unroll 1
  for (int c = 0; c < 64; ++c) {
    carry[(size_t)c*4096 + id] = r;
    r = fmaf(d32, r, E[(size_t)c*4096 + id]);
  }
}

__global__ __launch_bounds__(256) void scan_c(const float* __restrict__ Q,
    const float* __restrict__ K, const float* __restrict__ V,
    const float* __restrict__ dec_p, const float* __restrict__ carry,
    float* __restrict__ ret)
{
  int id  = blockIdx.x*256 + threadIdx.x;
  int c   = id >> 12;
  int rem = id & 4095;
  int b   = rem >> 10;
  int dc  = rem & 1023;
  float dec = dec_p[dc >> 6];
  size_t base = ((size_t)b*SEQ + (size_t)c*32)*DIM + dc;
  float r = carry[(size_t)c*4096 + rem];
  #pragma unroll 1
  for (int i = 0; i < 32; ++i) {
    int t = c*32 + i;
    float kv = K[base + (size_t)i*DIM] * V[base + (size_t)i*DIM];
    r = fmaf(dec, r, kv);
    ret[((size_t)t*BATCH + b)*DIM + dc] = Q[base + (size_t)i*DIM] * r;
  }
}

// ---------------- fp32 tiled GEMM: C[m,n] = sum_k X[m,k]*W[n,k] (+bias) -------
// MODE 0: C = XW^T + bias
// MODE 1: g = sigmoid(XW^T + bias) -> C;  u_out = (1-g)*inp
// MODE 2: C += XW^T
// MODE 3: outf[b,t,n] = XW^T + bias   (m = t*4+b scatter), float32 output
// MODE 4: C = XW^T
// 128x128 tile, 8x8 per thread. r2 showed 4x4/thread was DS-pipe-bound
// (24cyc LDS vs 16cyc VALU per kk); 8x8 gives max(48,64) for 64 fma = 1.5x.
// W-cols split as tx*4 and 64+tx*4 so Ws b128 reads are only 2-way bank
// conflicted (free per m136); Xs reads are 16-lane broadcasts (free).
#define GM 128
#define GN 128
#define GK 16
#define LDG 132

template<int MODE>
__global__ __launch_bounds__(256) void gemm_k(
    const float* __restrict__ X, const float* __restrict__ W,
    const float* __restrict__ bias, float* __restrict__ C,
    const float* __restrict__ inp, float* __restrict__ u_out,
    float* __restrict__ outf)
{
  __shared__ float Xs[GK][LDG];
  __shared__ float Ws[GK][LDG];
  const int tid = threadIdx.x;
  const int m0 = blockIdx.y * GM;
  const int n0 = blockIdx.x * GN;
  const int tx = tid & 15, ty = tid >> 4;
  v2f acc[8][4] = {};
  #pragma unroll 1
  for (int kb = 0; kb < DIM; kb += GK) {
    #pragma unroll
    for (int h = 0; h < 2; ++h) {
      int idx = tid + h*256;
      int r   = idx >> 2;         // 0..127
      int kc  = (idx & 3) << 2;   // 0,4,8,12
      float4 xv = *(const float4*)(X + (size_t)(m0+r)*DIM + kb + kc);
      Xs[kc+0][r] = xv.x; Xs[kc+1][r] = xv.y;
      Xs[kc+2][r] = xv.z; Xs[kc+3][r] = xv.w;
      float4 wv2 = *(const float4*)(W + (size_t)(n0+r)*DIM + kb + kc);
      Ws[kc+0][r] = wv2.x; Ws[kc+1][r] = wv2.y;
      Ws[kc+2][r] = wv2.z; Ws[kc+3][r] = wv2.w;
    }
    __syncthreads();
    #pragma unroll
    for (int kk = 0; kk < GK; ++kk) {
      float4 a0 = *(const float4*)&Xs[kk][ty*8];
      float4 a1 = *(const float4*)&Xs[kk][ty*8 + 4];
      float4 w0 = *(const float4*)&Ws[kk][tx*4];        // cols tx*4..+3
      float4 w1 = *(const float4*)&Ws[kk][64 + tx*4];   // cols 64+tx*4..+3
      v2f wv[4] = {{w0.x,w0.y},{w0.z,w0.w},{w1.x,w1.y},{w1.z,w1.w}};
      float av[8] = {a0.x,a0.y,a0.z,a0.w,a1.x,a1.y,a1.z,a1.w};
      #pragma unroll
      for (int i = 0; i < 8; ++i) {
        v2f ab = {av[i], av[i]};
        #pragma unroll
        for (int j = 0; j < 4; ++j)
          acc[i][j] = __builtin_elementwise_fma(ab, wv[j], acc[i][j]);
      }
    }
    __syncthreads();
  }
  float bj[8];
  #pragma unroll
  for (int j = 0; j < 8; ++j) {
    int n = n0 + ((j < 4) ? (tx*4 + j) : (64 + tx*4 + (j - 4)));
    bj[j] = (MODE == 0 || MODE == 1 || MODE == 3) ? bias[n] : 0.f;
  }
  #pragma unroll
  for (int i = 0; i < 8; ++i) {
    int m = m0 + ty*8 + i;
    #pragma unroll
    for (int j = 0; j < 8; ++j) {
      int n = n0 + ((j < 4) ? (tx*4 + j) : (64 + tx*4 + (j - 4)));
      size_t off = (size_t)m*DIM + n;
      float vv = acc[i][j >> 1][j & 1] + bj[j];
      if (MODE == 2) vv += C[off];
      if (MODE == 1) {
        float gv = 1.f/(1.f + expf(-vv));
        C[off] = gv;
        u_out[off] = (1.f - gv) * inp[off];
      } else if (MODE == 3) {
        outf[((size_t)(m & 3)*SEQ + (size_t)(m >> 2))*DIM + n] = vv;
      } else {
        C[off] = vv;
      }
    }
  }
}

// ---------------- sequential recurrence: s_t = tanh((g_t*s_{t-1})@A^T + d_t) --
// 4 independent batch chains, 16 blocks x 512 threads each, 64 A-rows/block
// in registers (8 lanes/row, k split 8x128).
//
// Sync: 2-slot ring sf[2][B][512] of PACKED words {f32 x[2r], f32 x[2r+1]},
// each float carrying a 1-bit step tag in its mantissa LSB
// (tag(t) = ((t+2)>>1)&1: distinguishes t from t-2 within a slot; memset-0
// words fail the t=1 check; LSB error 2^-24 << tolerance). One 8B word per
// thread per step -> poll = ONE load; the 8B store is atomic so checking one
// LSB covers both floats.
//
// Critical-path ordering: at the END of step t each thread PRE-ISSUES two
// staggered samples of its step-(t) word (after the publish stores, pinned
// by an asm memory barrier). Their IC-read happens while the producer tail/
// store-ack completes, so discovery at t+1 usually costs ~0 extra RT.
// xs is double-buffered -> no end-of-step barrier (waves drift at most one
// segment; all t-1 LDS reads provably drained by t's stage barrier).
// Ring reuse safety: producer at t+2 overwrites slot t&1 only after seeing
// all tag(t+1) words, which requires every block to have passed its t+1
// stage barrier, i.e. consumed slot t&1.
#define RBLK 64

__global__ __launch_bounds__(512, 2) void recur_k(
    const float* __restrict__ A, const float* __restrict__ g,
    const float* __restrict__ dpre, float* __restrict__ s,
    unsigned long long* __restrict__ sf)
{
  __shared__ __align__(16) float xs[2][8*132 + 4];
  const int tid = threadIdx.x;
  const int w   = tid >> 6;                 // wave 0..7
  const int ln  = tid & 63;
  const int b   = blockIdx.x >> 4;          // batch 0..3
  const int blk = blockIdx.x & 15;          // block within batch
  const int row = blk*64 + w*8 + (ln >> 3); // global row 0..1023
  const int ks  = ln & 7;                   // k-slice (128 floats)

  const size_t slotstride = (size_t)BATCH*512;     // ull words per ring slot
  unsigned long long* sfb = sf + (size_t)b*512;    // this batch, slot 0

  // A fragment: (row, k in [ks*128, ks*128+128))
  float4 areg[32];
  #pragma unroll
  for (int j = 0; j < 32; ++j)
    areg[j] = *(const float4*)(A + (size_t)row*DIM + ks*128 + 4*j);
  const v2f* a2 = reinterpret_cast<const v2f*>(areg);

  // x-staging slot for this thread: floats [2*tid, 2*tid+1] of x
  const int xoff = (tid >> 6)*132 + ((2*tid) & 127);

  // prologue prefetch (t=0); gvc here is unused (t=0 has no stage) but cheap
  float2 gvc = *(const float2*)(g + (size_t)b*DIM + 2*tid);
  float  dvc = (ks == 0) ? dpre[(size_t)b*DIM + row] : 0.f;
  unsigned long long sampA = 0, sampB = 0;

  #pragma unroll 1
  for (int t = 0; t < SEQ; ++t) {
    const int buf = t & 1;
    v2f acc0 = {0.f,0.f}, acc1 = {0.f,0.f}, acc2 = {0.f,0.f}, acc3 = {0.f,0.f};
    if (t > 0) {
      const unsigned wl = ((unsigned)(t + 1) >> 1) & 1u;  // tag(t-1)
      unsigned long long* pw =
          sfb + (size_t)((t - 1) & 1)*slotstride + tid;
      union { unsigned long long u; float f[2]; } wv;
      if ((unsigned)(sampA & 1u) == wl)       wv.u = sampA;
      else if ((unsigned)(sampB & 1u) == wl)  wv.u = sampB;
      else {
        int guard = 0;
        for (;;) {
          unsigned long long x0 = __hip_atomic_load(pw, __ATOMIC_RELAXED,
                                                    __HIP_MEMORY_SCOPE_AGENT);
          unsigned long long x1 = __hip_atomic_load(pw, __ATOMIC_RELAXED,
                                                    __HIP_MEMORY_SCOPE_AGENT);
          if ((unsigned)(x0 & 1u) == wl) { wv.u = x0; break; }
          if ((unsigned)(x1 & 1u) == wl) { wv.u = x1; break; }
          if (++guard > (1 << 22))       { wv.u = x1; break; }
        }
      }

      // stage x = g * s[t-1][b]
      *(float2*)(xs[buf] + xoff) = make_float2(gvc.x * wv.f[0],
                                               gvc.y * wv.f[1]);
      asm volatile("s_waitcnt lgkmcnt(0)\n\ts_barrier" ::: "memory");

      // matvec: this lane covers k-slice ks of its row (packed fp32)
      const float* xb = xs[buf] + ks*132;
      #pragma unroll
      for (int j = 0; j < 32; j += 4) {
        float4 x0 = *(const float4*)(xb + 4*j);
        float4 x1 = *(const float4*)(xb + 4*j + 4);
        float4 x2 = *(const float4*)(xb + 4*j + 8);
        float4 x3 = *(const float4*)(xb + 4*j + 12);
        v2f x0l = {x0.x, x0.y}, x0h = {x0.z, x0.w};
        v2f x1l = {x1.x, x1.y}, x1h = {x1.z, x1.w};
        v2f x2l = {x2.x, x2.y}, x2h = {x2.z, x2.w};
        v2f x3l = {x3.x, x3.y}, x3h = {x3.z, x3.w};
        acc0 = __builtin_elementwise_fma(a2[2*j+0], x0l, acc0);
        acc0 = __builtin_elementwise_fma(a2[2*j+1], x0h, acc0);
        acc1 = __builtin_elementwise_fma(a2[2*j+2], x1l, acc1);
        acc1 = __builtin_elementwise_fma(a2[2*j+3], x1h, acc1);
        acc2 = __builtin_elementwise_fma(a2[2*j+4], x2l, acc2);
        acc2 = __builtin_elementwise_fma(a2[2*j+5], x2h, acc2);
        acc3 = __builtin_elementwise_fma(a2[2*j+6], x3l, acc3);
        acc3 = __builtin_elementwise_fma(a2[2*j+7], x3h, acc3);
      }
    }
    v2f accp = (acc0 + acc1) + (acc2 + acc3);
    float sum = accp.x + accp.y;
    sum += __shfl_xor(sum, 1, 64);
    sum += __shfl_xor(sum, 2, 64);
    sum += __shfl_xor(sum, 4, 64);
    float val = 0.f;
    if (ks == 0) {
      // fast tanh: 1 - 2/(e^{2x}+1); exp2 overflow/underflow saturates to +-1
      float zz  = sum + dvc;
      float e2x = __builtin_amdgcn_exp2f(zz * 2.8853900817779268f);
      val = 1.0f - 2.0f * __builtin_amdgcn_rcpf(e2x + 1.0f);
    }
    // pack rows (even,odd): partner val from lane ln+8 (also a ks==0 lane)
    float pv = __shfl_xor(val, 8, 64);
    const unsigned tg = ((unsigned)(t + 2) >> 1) & 1u;
    if ((ln & 15) == 0) {
      union { unsigned long long u; unsigned ui[2]; } pk;
      pk.ui[0] = (__float_as_uint(val) & ~1u) | tg;
      pk.ui[1] = (__float_as_uint(pv)  & ~1u) | tg;
      __hip_atomic_store(sfb + (size_t)(t & 1)*slotstride + (row >> 1), pk.u,
                         __ATOMIC_RELAXED, __HIP_MEMORY_SCOPE_AGENT);
    }
    if (ks == 0)
      s[((size_t)t*4 + b)*DIM + row] = val;   // plain store for output GEMM

    // prefetch + PRE-ISSUE next step's poll samples (overlap store ack / tail)
    if (t + 1 < SEQ) {
      gvc = *(const float2*)(g + ((size_t)(t + 1)*4 + b)*DIM + 2*tid);
      dvc = (ks == 0) ? dpre[((size_t)(t + 1)*4 + b)*DIM + row] : 0.f;
      unsigned long long* pw1 = sfb + (size_t)(t & 1)*slotstride + tid;
      sampA = __hip_atomic_load(pw1, __ATOMIC_RELAXED,
                                __HIP_MEMORY_SCOPE_AGENT);
      sampB = __hip_atomic_load(pw1, __ATOMIC_RELAXED,
                                __HIP_MEMORY_SCOPE_AGENT);
      asm volatile("" ::: "memory");   // pin issue point of the samples
    }
    // no end barrier: xs double-buffered, polls re-sync waves
  }
}

// ------------------------------------------------------------------------------
extern "C" void kernel_launch(void* const* d_in, const int* in_sizes, int n_in,
                              void* d_out, int out_size, void* d_ws, size_t ws_size,
                              hipStream_t stream)
{
  (void)in_sizes; (void)n_in; (void)out_size;
  const float* q   = (const float*)d_in[0];
  const float* k   = (const float*)d_in[1];
  const float* v   = (const float*)d_in[2];
  const float* Wi  = (const float*)d_in[3];
  const float* bi  = (const float*)d_in[4];
  const float* Wg  = (const float*)d_in[5];
  const float* bg  = (const float*)d_in[6];
  const float* A   = (const float*)d_in[7];
  const float* Bm  = (const float*)d_in[8];
  const float* Wo  = (const float*)d_in[9];
  const float* bo  = (const float*)d_in[10];
  const float* dec = (const float*)d_in[11];

  const size_t sf_bytes = (size_t)2*BATCH*512*sizeof(unsigned long long); // 32KB
  size_t need = (4*BIGN + 2*(size_t)64*4096)*sizeof(float) + sf_bytes;
  if (ws_size < need) return;

  float* b0 = (float*)d_ws;          // ret -> u -> s
  float* b1 = b0 + BIGN;             // inp
  float* b2 = b1 + BIGN;             // g
  float* b3 = b2 + BIGN;             // d  (pre-activation constant)
  float* E     = b3 + BIGN;
  float* carry = E + (size_t)64*4096;
  unsigned long long* sf = (unsigned long long*)(carry + (size_t)64*4096);
  float* outp  = (float*)d_out;

  hipMemsetAsync(sf, 0, sf_bytes, stream);

  scan_a<<<1024, 256, 0, stream>>>(k, v, dec, E);
  scan_b<<<16,   256, 0, stream>>>(E, dec, carry);
  scan_c<<<1024, 256, 0, stream>>>(q, k, v, dec, carry, b0);

  dim3 gg(DIM/GN, MROWS/GM);   // (8, 64)
  gemm_k<0><<<gg, 256, 0, stream>>>(b0, Wi, bi, b1, nullptr, nullptr, nullptr); // inp
  gemm_k<1><<<gg, 256, 0, stream>>>(b1, Wg, bg, b2, b1, b0, nullptr);           // g, u
  gemm_k<4><<<gg, 256, 0, stream>>>(b0, A,  nullptr, b3, nullptr, nullptr, nullptr); // d  = u@A^T
  gemm_k<2><<<gg, 256, 0, stream>>>(b1, Bm, nullptr, b3, nullptr, nullptr, nullptr); // d += inp@Bm^T

  recur_k<<<RBLK, 512, 0, stream>>>(A, b2, b3, b0, sf);                         // s

  gemm_k<3><<<gg, 256, 0, stream>>>(b0, Wo, bo, nullptr, nullptr, nullptr, outp); // out
}